// Round 3
// baseline (153.847 us; speedup 1.0000x reference)
//
#include <hip/hip_runtime.h>

typedef unsigned short u16;
typedef __attribute__((ext_vector_type(8))) short short8_t;   // 8 bf16 = 4 VGPRs
typedef __attribute__((ext_vector_type(4))) float f32x4;      // MFMA accumulator

#define N_SAMP 256
#define IN_F   1024
#define OUT_F  128
#define KDIM   32
#define JTOT   (OUT_F * KDIM)   // 4096
#define OUT_ROW (IN_F + OUT_F)  // 1152

__device__ __forceinline__ u16 f2bf(float f) {
    union { float f; unsigned u; } v; v.f = f;
    unsigned r = v.u + 0x7FFFu + ((v.u >> 16) & 1u);   // RNE
    return (u16)(r >> 16);
}

// ===========================================================================
// MAIN PATH (bf16 MFMA, M stored transposed: Mt[j][n], j = o*32+k)
// ===========================================================================

// --- x -> out[:, :1024] copy, o_b init to -1, and x -> bf16 A' [256][1024] ---
__global__ __launch_bounds__(256) void copy_init_conv(const float* __restrict__ x,
                                                      float* __restrict__ out,
                                                      u16* __restrict__ At) {
    int n = blockIdx.x, t = threadIdx.x;
    float4 v = reinterpret_cast<const float4*>(x + (size_t)n * IN_F)[t];
    reinterpret_cast<float4*>(out + (size_t)n * OUT_ROW)[t] = v;
    ushort4 b;
    b.x = f2bf(v.x); b.y = f2bf(v.y); b.z = f2bf(v.z); b.w = f2bf(v.w);
    reinterpret_cast<ushort4*>(At + (size_t)n * IN_F)[t] = b;
    if (t < OUT_F) out[(size_t)n * OUT_ROW + IN_F + t] = -1.0f;
}

// --- T [1024 k][4096 j] fp32  ->  Bt [4096 j][1024 k] bf16 (tiled transpose) ---
__global__ __launch_bounds__(256) void convT_kernel(const float* __restrict__ T,
                                                    u16* __restrict__ Bt) {
    __shared__ float Ls[64 * 65];                 // odd stride -> conflict-light
    const int t = threadIdx.x;
    const int j0 = blockIdx.x * 64, k0 = blockIdx.y * 64;
    const int r = t >> 2, c4 = t & 3;

    const float4* src = reinterpret_cast<const float4*>(T + (size_t)(k0 + r) * JTOT + j0 + c4 * 16);
    float4 v0 = src[0], v1 = src[1], v2 = src[2], v3 = src[3];
    float vv[16] = {v0.x,v0.y,v0.z,v0.w, v1.x,v1.y,v1.z,v1.w,
                    v2.x,v2.y,v2.z,v2.w, v3.x,v3.y,v3.z,v3.w};
#pragma unroll
    for (int i = 0; i < 16; ++i) Ls[r * 65 + c4 * 16 + i] = vv[i];
    __syncthreads();

    unsigned pk[8];
#pragma unroll
    for (int i = 0; i < 8; ++i) {
        u16 lo = f2bf(Ls[(c4 * 16 + 2 * i    ) * 65 + r]);
        u16 hi = f2bf(Ls[(c4 * 16 + 2 * i + 1) * 65 + r]);
        pk[i] = (unsigned)lo | ((unsigned)hi << 16);
    }
    uint4* dst = reinterpret_cast<uint4*>(Bt + (size_t)(j0 + r) * IN_F + k0 + c4 * 16);
    dst[0] = make_uint4(pk[0], pk[1], pk[2], pk[3]);
    dst[1] = make_uint4(pk[4], pk[5], pk[6], pk[7]);
}

// --- Mt[4096][256] = Bt[4096][1024] x At[256][1024]^T via 16x16x32 bf16 MFMA ---
// block: 128 thr = 2 waves side-by-side in j; tile 64j x 32n; grid (64, 8) = 512 blocks
#define LDB 136   // 128 + 8 bf16 pad: row stride 272 B (16B-aligned, bank-step 17)
__global__ __launch_bounds__(128) void mfma_gemm(const u16* __restrict__ At,
                                                 const u16* __restrict__ Bt,
                                                 float* __restrict__ Mt) {
    __shared__ u16 Bs[64 * LDB];   // j-tile
    __shared__ u16 As[32 * LDB];   // n-tile
    const int t = threadIdx.x;
    const int w = t >> 6, l = t & 63;
    const int jb = blockIdx.x * 64, nb = blockIdx.y * 32;
    const int rb = t >> 1, hb = t & 1;   // Bt staging: row (0..63), k-half
    const int ra = t >> 2, qa = t & 3;   // At staging: row (0..31), k-quarter

    f32x4 acc00 = {0.f,0.f,0.f,0.f}, acc01 = {0.f,0.f,0.f,0.f};
    f32x4 acc10 = {0.f,0.f,0.f,0.f}, acc11 = {0.f,0.f,0.f,0.f};

    float4 sb[8], sa[4];
    auto LOADG = [&](int it) {
        const float4* gb = reinterpret_cast<const float4*>(Bt + (size_t)(jb + rb) * IN_F + it * 128 + hb * 64);
#pragma unroll
        for (int i = 0; i < 8; ++i) sb[i] = gb[i];
        const float4* ga = reinterpret_cast<const float4*>(At + (size_t)(nb + ra) * IN_F + it * 128 + qa * 32);
#pragma unroll
        for (int i = 0; i < 4; ++i) sa[i] = ga[i];
    };
    auto STORE = [&]() {
#pragma unroll
        for (int i = 0; i < 8; ++i) *reinterpret_cast<float4*>(&Bs[rb * LDB + hb * 64 + i * 8]) = sb[i];
#pragma unroll
        for (int i = 0; i < 4; ++i) *reinterpret_cast<float4*>(&As[ra * LDB + qa * 32 + i * 8]) = sa[i];
    };

    LOADG(0); STORE(); __syncthreads();

    for (int it = 0; it < 8; ++it) {
        if (it < 7) LOADG(it + 1);          // issue next tile early (hide under MFMA)
#pragma unroll
        for (int s = 0; s < 4; ++s) {
            const int co = s * 32 + 8 * (l >> 4);     // same assumed k-map for A and B
            short8_t a0 = *reinterpret_cast<const short8_t*>(&Bs[(w * 32 +      (l & 15)) * LDB + co]);
            short8_t a1 = *reinterpret_cast<const short8_t*>(&Bs[(w * 32 + 16 + (l & 15)) * LDB + co]);
            short8_t b0 = *reinterpret_cast<const short8_t*>(&As[(          (l & 15)) * LDB + co]);
            short8_t b1 = *reinterpret_cast<const short8_t*>(&As[(     16 + (l & 15)) * LDB + co]);
            acc00 = __builtin_amdgcn_mfma_f32_16x16x32_bf16(a0, b0, acc00, 0, 0, 0);
            acc01 = __builtin_amdgcn_mfma_f32_16x16x32_bf16(a0, b1, acc01, 0, 0, 0);
            acc10 = __builtin_amdgcn_mfma_f32_16x16x32_bf16(a1, b0, acc10, 0, 0, 0);
            acc11 = __builtin_amdgcn_mfma_f32_16x16x32_bf16(a1, b1, acc11, 0, 0, 0);
        }
        __syncthreads();
        if (it < 7) { STORE(); __syncthreads(); }
    }

    // C/D layout (m89-verified): col = lane&15 (n-index), row = 4*(lane>>4)+reg (j-index)
    const int jrow = jb + w * 32 + (l >> 4) * 4;
    const int ncol = nb + (l & 15);
#pragma unroll
    for (int r = 0; r < 4; ++r) {
        Mt[(size_t)(jrow + r     ) * N_SAMP + ncol     ] = acc00[r];
        Mt[(size_t)(jrow + r     ) * N_SAMP + ncol + 16] = acc01[r];
        Mt[(size_t)(jrow + 16 + r) * N_SAMP + ncol     ] = acc10[r];
        Mt[(size_t)(jrow + 16 + r) * N_SAMP + ncol + 16] = acc11[r];
    }
}

// --- pairwise exp(-L1) from Mt[j][n]: wave-per-o, 4 n-rows per thread ---
// grid (32 o-groups, 16 m-chunks) = 512 blocks, 256 thr
__global__ __launch_bounds__(256) void dist2_kernel(const float* __restrict__ Mt,
                                                    float* __restrict__ out) {
    __shared__ float Mo[4][16][36];   // [wave(o)][m][k], padded, rows 16B-aligned
    const int t = threadIdx.x, w = t >> 6, l = t & 63;
    const int o  = blockIdx.x * 4 + w;
    const int mb = blockIdx.y * 16;

    float r0[KDIM], r1[KDIM], r2[KDIM], r3[KDIM];
#pragma unroll
    for (int k = 0; k < KDIM; ++k) {
        const float* p = Mt + (size_t)(o * KDIM + k) * N_SAMP + l;   // lane-coalesced
        r0[k] = p[0]; r1[k] = p[64]; r2[k] = p[128]; r3[k] = p[192];
    }
    {
        const int m = l & 15, kb = (l >> 4) * 8;
#pragma unroll
        for (int kk = 0; kk < 8; ++kk)
            Mo[w][m][kb + kk] = Mt[(size_t)(o * KDIM + kb + kk) * N_SAMP + mb + m];
    }
    __syncthreads();

    float acc0 = 0.f, acc1 = 0.f, acc2 = 0.f, acc3 = 0.f;
    for (int mi = 0; mi < 16; ++mi) {
        float mo[KDIM];
#pragma unroll
        for (int i = 0; i < 8; ++i)
            *reinterpret_cast<float4*>(&mo[i * 4]) =
                *reinterpret_cast<const float4*>(&Mo[w][mi][i * 4]);   // broadcast

#define DIST_N(RR, ACC) {                                              \
        float d0 = 0.f, d1 = 0.f, d2 = 0.f, d3 = 0.f;                  \
        _Pragma("unroll")                                              \
        for (int k4 = 0; k4 < 8; ++k4) {                               \
            d0 += fabsf(RR[k4*4+0] - mo[k4*4+0]);                      \
            d1 += fabsf(RR[k4*4+1] - mo[k4*4+1]);                      \
            d2 += fabsf(RR[k4*4+2] - mo[k4*4+2]);                      \
            d3 += fabsf(RR[k4*4+3] - mo[k4*4+3]);                      \
        }                                                              \
        ACC += __expf(-((d0 + d1) + (d2 + d3))); }

        DIST_N(r0, acc0) DIST_N(r1, acc1) DIST_N(r2, acc2) DIST_N(r3, acc3)
#undef DIST_N
    }
    const int ob = IN_F + o;
    atomicAdd(&out[(size_t)(l      ) * OUT_ROW + ob], acc0);
    atomicAdd(&out[(size_t)(l +  64) * OUT_ROW + ob], acc1);
    atomicAdd(&out[(size_t)(l + 128) * OUT_ROW + ob], acc2);
    atomicAdd(&out[(size_t)(l + 192) * OUT_ROW + ob], acc3);
}

// ===========================================================================
// FALLBACK PATH (round-1 proven kernels; used only if ws is too small)
// ===========================================================================
__global__ __launch_bounds__(256) void copy_init_kernel(const float* __restrict__ x,
                                                        float* __restrict__ out) {
    int n = blockIdx.x, t = threadIdx.x;
    reinterpret_cast<float4*>(out + (size_t)n * OUT_ROW)[t] =
        reinterpret_cast<const float4*>(x + (size_t)n * IN_F)[t];
    if (t < OUT_F) out[(size_t)n * OUT_ROW + IN_F + t] = -1.0f;
}

#define BM 64
#define BN 64
#define BK 16
#define AS_STRIDE 68
__global__ __launch_bounds__(256) void gemm_kernel(const float* __restrict__ x,
                                                   const float* __restrict__ T,
                                                   float* __restrict__ M) {
    __shared__ float As_[BK][AS_STRIDE];
    __shared__ float Bs_[BK][BN];
    const int jb = blockIdx.x * BN, nb = blockIdx.y * BM;
    const int t = threadIdx.x, tx = t & 15, ty = t >> 4;
    float acc[4][4] = {};
    for (int k0 = 0; k0 < IN_F; k0 += BK) {
        {
            int row = t >> 2, cg = (t & 3) * 4;
            float4 v = *reinterpret_cast<const float4*>(&x[(size_t)(nb + row) * IN_F + k0 + cg]);
            As_[cg + 0][row] = v.x; As_[cg + 1][row] = v.y;
            As_[cg + 2][row] = v.z; As_[cg + 3][row] = v.w;
        }
        {
            int r = t >> 4, cg = (t & 15) * 4;
            *reinterpret_cast<float4*>(&Bs_[r][cg]) =
                *reinterpret_cast<const float4*>(&T[(size_t)(k0 + r) * JTOT + jb + cg]);
        }
        __syncthreads();
#pragma unroll
        for (int kk = 0; kk < BK; ++kk) {
            float4 av = *reinterpret_cast<const float4*>(&As_[kk][ty * 4]);
            float4 bv = *reinterpret_cast<const float4*>(&Bs_[kk][tx * 4]);
            float a[4] = {av.x, av.y, av.z, av.w}, b[4] = {bv.x, bv.y, bv.z, bv.w};
#pragma unroll
            for (int i = 0; i < 4; ++i)
#pragma unroll
                for (int j = 0; j < 4; ++j) acc[i][j] += a[i] * b[j];
        }
        __syncthreads();
    }
#pragma unroll
    for (int i = 0; i < 4; ++i) {
        int n = nb + ty * 4 + i;
        float4 v = make_float4(acc[i][0], acc[i][1], acc[i][2], acc[i][3]);
        *reinterpret_cast<float4*>(&M[(size_t)n * JTOT + jb + tx * 4]) = v;
    }
}

__global__ __launch_bounds__(256) void dist_kernel(const float* __restrict__ M,
                                                   float* __restrict__ out) {
    __shared__ float Mo_[64][KDIM];
    const int o = blockIdx.x >> 2, chunk = blockIdx.x & 3, t = threadIdx.x;
    float r[KDIM];
    const float4* mrow = reinterpret_cast<const float4*>(&M[(size_t)t * JTOT + o * KDIM]);
#pragma unroll
    for (int f = 0; f < 8; ++f) {
        float4 v = mrow[f];
        r[f*4+0]=v.x; r[f*4+1]=v.y; r[f*4+2]=v.z; r[f*4+3]=v.w;
    }
    const int mbase = chunk * 64;
    {
        int row = t >> 3, f4 = t & 7;
        *reinterpret_cast<float4*>(&Mo_[row][f4*4]) =
            *reinterpret_cast<const float4*>(&M[(size_t)(mbase+row)*JTOT + o*KDIM + f4*4]);
        *reinterpret_cast<float4*>(&Mo_[row+32][f4*4]) =
            *reinterpret_cast<const float4*>(&M[(size_t)(mbase+row+32)*JTOT + o*KDIM + f4*4]);
    }
    __syncthreads();
    float acc = 0.f;
    for (int m = 0; m < 64; ++m) {
        float d = 0.f;
#pragma unroll
        for (int k = 0; k < KDIM; ++k) d += fabsf(r[k] - Mo_[m][k]);
        acc += __expf(-d);
    }
    atomicAdd(&out[(size_t)t * OUT_ROW + IN_F + o], acc);
}

// ===========================================================================
extern "C" void kernel_launch(void* const* d_in, const int* in_sizes, int n_in,
                              void* d_out, int out_size, void* d_ws, size_t ws_size,
                              hipStream_t stream) {
    const float* x = (const float*)d_in[0];   // [256,1024]
    const float* T = (const float*)d_in[1];   // [1024,4096]
    float* out = (float*)d_out;               // [256,1152]

    const size_t MT_BYTES = (size_t)JTOT * N_SAMP * 4;        // 4 MiB
    const size_t AT_BYTES = (size_t)N_SAMP * IN_F * 2;        // 0.5 MiB
    const size_t BT_BYTES = (size_t)JTOT * IN_F * 2;          // 8 MiB

    if (ws_size >= MT_BYTES + AT_BYTES + BT_BYTES) {
        float* Mt = (float*)d_ws;
        u16*   At = (u16*)((char*)d_ws + MT_BYTES);
        u16*   Bt = (u16*)((char*)d_ws + MT_BYTES + AT_BYTES);

        copy_init_conv<<<N_SAMP, 256, 0, stream>>>(x, out, At);
        convT_kernel<<<dim3(JTOT / 64, IN_F / 64), 256, 0, stream>>>(T, Bt);
        mfma_gemm<<<dim3(JTOT / 64, N_SAMP / 32), 128, 0, stream>>>(At, Bt, Mt);
        dist2_kernel<<<dim3(OUT_F / 4, N_SAMP / 16), 256, 0, stream>>>(Mt, out);
    } else {
        float* M = (float*)d_ws;              // 4 MiB (proven available in r1)
        copy_init_kernel<<<N_SAMP, 256, 0, stream>>>(x, out);
        dim3 ggrid(JTOT / BN, N_SAMP / BM);
        gemm_kernel<<<ggrid, 256, 0, stream>>>(x, T, M);
        dist_kernel<<<OUT_F * 4, 256, 0, stream>>>(M, out);
    }
}

// Round 4
// 120.457 us; speedup vs baseline: 1.2772x; 1.2772x over previous
//
#include <hip/hip_runtime.h>

typedef unsigned short u16;
typedef __attribute__((ext_vector_type(8))) short short8_t;   // 8 bf16 = 4 VGPRs
typedef __attribute__((ext_vector_type(4))) float f32x4;      // MFMA accumulator

#define N_SAMP 256
#define IN_F   1024
#define OUT_F  128
#define KDIM   32
#define JTOT   (OUT_F * KDIM)   // 4096
#define OUT_ROW (IN_F + OUT_F)  // 1152

#define CHUNKS 8                 // m-chunks for dist partials
#define MPC    32                // m per chunk (per block)
#define MPW    8                 // m per wave

__device__ __forceinline__ u16 f2bf(float f) {
    union { float f; unsigned u; } v; v.f = f;
    unsigned r = v.u + 0x7FFFu + ((v.u >> 16) & 1u);   // RNE
    return (u16)(r >> 16);
}

// ===========================================================================
// MAIN PATH (bf16 MFMA, M stored transposed: Mt[j][n], j = o*32+k)
// ===========================================================================

// --- x -> out[:, :1024] copy and x -> bf16 A' [256][1024] ---
__global__ __launch_bounds__(256) void copy_init_conv(const float* __restrict__ x,
                                                      float* __restrict__ out,
                                                      u16* __restrict__ At) {
    int n = blockIdx.x, t = threadIdx.x;
    float4 v = reinterpret_cast<const float4*>(x + (size_t)n * IN_F)[t];
    reinterpret_cast<float4*>(out + (size_t)n * OUT_ROW)[t] = v;
    ushort4 b;
    b.x = f2bf(v.x); b.y = f2bf(v.y); b.z = f2bf(v.z); b.w = f2bf(v.w);
    reinterpret_cast<ushort4*>(At + (size_t)n * IN_F)[t] = b;
}

// --- T [1024 k][4096 j] fp32  ->  Bt [4096 j][1024 k] bf16 (tiled transpose) ---
__global__ __launch_bounds__(256) void convT_kernel(const float* __restrict__ T,
                                                    u16* __restrict__ Bt) {
    __shared__ float Ls[64 * 65];                 // odd stride -> conflict-light
    const int t = threadIdx.x;
    const int j0 = blockIdx.x * 64, k0 = blockIdx.y * 64;
    const int r = t >> 2, c4 = t & 3;

    const float4* src = reinterpret_cast<const float4*>(T + (size_t)(k0 + r) * JTOT + j0 + c4 * 16);
    float4 v0 = src[0], v1 = src[1], v2 = src[2], v3 = src[3];
    float vv[16] = {v0.x,v0.y,v0.z,v0.w, v1.x,v1.y,v1.z,v1.w,
                    v2.x,v2.y,v2.z,v2.w, v3.x,v3.y,v3.z,v3.w};
#pragma unroll
    for (int i = 0; i < 16; ++i) Ls[r * 65 + c4 * 16 + i] = vv[i];
    __syncthreads();

    unsigned pk[8];
#pragma unroll
    for (int i = 0; i < 8; ++i) {
        u16 lo = f2bf(Ls[(c4 * 16 + 2 * i    ) * 65 + r]);
        u16 hi = f2bf(Ls[(c4 * 16 + 2 * i + 1) * 65 + r]);
        pk[i] = (unsigned)lo | ((unsigned)hi << 16);
    }
    uint4* dst = reinterpret_cast<uint4*>(Bt + (size_t)(j0 + r) * IN_F + k0 + c4 * 16);
    dst[0] = make_uint4(pk[0], pk[1], pk[2], pk[3]);
    dst[1] = make_uint4(pk[4], pk[5], pk[6], pk[7]);
}

// --- Mt[4096][256] = Bt[4096][1024] x At[256][1024]^T via 16x16x32 bf16 MFMA ---
#define LDB 136   // 128 + 8 bf16 pad: row stride 272 B (16B-aligned, bank-step 17)
__global__ __launch_bounds__(128) void mfma_gemm(const u16* __restrict__ At,
                                                 const u16* __restrict__ Bt,
                                                 float* __restrict__ Mt) {
    __shared__ u16 Bs[64 * LDB];   // j-tile
    __shared__ u16 As[32 * LDB];   // n-tile
    const int t = threadIdx.x;
    const int w = t >> 6, l = t & 63;
    const int jb = blockIdx.x * 64, nb = blockIdx.y * 32;
    const int rb = t >> 1, hb = t & 1;   // Bt staging: row (0..63), k-half
    const int ra = t >> 2, qa = t & 3;   // At staging: row (0..31), k-quarter

    f32x4 acc00 = {0.f,0.f,0.f,0.f}, acc01 = {0.f,0.f,0.f,0.f};
    f32x4 acc10 = {0.f,0.f,0.f,0.f}, acc11 = {0.f,0.f,0.f,0.f};

    float4 sb[8], sa[4];
    auto LOADG = [&](int it) {
        const float4* gb = reinterpret_cast<const float4*>(Bt + (size_t)(jb + rb) * IN_F + it * 128 + hb * 64);
#pragma unroll
        for (int i = 0; i < 8; ++i) sb[i] = gb[i];
        const float4* ga = reinterpret_cast<const float4*>(At + (size_t)(nb + ra) * IN_F + it * 128 + qa * 32);
#pragma unroll
        for (int i = 0; i < 4; ++i) sa[i] = ga[i];
    };
    auto STORE = [&]() {
#pragma unroll
        for (int i = 0; i < 8; ++i) *reinterpret_cast<float4*>(&Bs[rb * LDB + hb * 64 + i * 8]) = sb[i];
#pragma unroll
        for (int i = 0; i < 4; ++i) *reinterpret_cast<float4*>(&As[ra * LDB + qa * 32 + i * 8]) = sa[i];
    };

    LOADG(0); STORE(); __syncthreads();

    for (int it = 0; it < 8; ++it) {
        if (it < 7) LOADG(it + 1);          // issue next tile early (hide under MFMA)
#pragma unroll
        for (int s = 0; s < 4; ++s) {
            const int co = s * 32 + 8 * (l >> 4);     // same assumed k-map for A and B
            short8_t a0 = *reinterpret_cast<const short8_t*>(&Bs[(w * 32 +      (l & 15)) * LDB + co]);
            short8_t a1 = *reinterpret_cast<const short8_t*>(&Bs[(w * 32 + 16 + (l & 15)) * LDB + co]);
            short8_t b0 = *reinterpret_cast<const short8_t*>(&As[(          (l & 15)) * LDB + co]);
            short8_t b1 = *reinterpret_cast<const short8_t*>(&As[(     16 + (l & 15)) * LDB + co]);
            acc00 = __builtin_amdgcn_mfma_f32_16x16x32_bf16(a0, b0, acc00, 0, 0, 0);
            acc01 = __builtin_amdgcn_mfma_f32_16x16x32_bf16(a0, b1, acc01, 0, 0, 0);
            acc10 = __builtin_amdgcn_mfma_f32_16x16x32_bf16(a1, b0, acc10, 0, 0, 0);
            acc11 = __builtin_amdgcn_mfma_f32_16x16x32_bf16(a1, b1, acc11, 0, 0, 0);
        }
        __syncthreads();
        if (it < 7) { STORE(); __syncthreads(); }
    }

    // C/D layout (m89-verified): col = lane&15 (n-index), row = 4*(lane>>4)+reg (j-index)
    const int jrow = jb + w * 32 + (l >> 4) * 4;
    const int ncol = nb + (l & 15);
#pragma unroll
    for (int r = 0; r < 4; ++r) {
        Mt[(size_t)(jrow + r     ) * N_SAMP + ncol     ] = acc00[r];
        Mt[(size_t)(jrow + r     ) * N_SAMP + ncol + 16] = acc01[r];
        Mt[(size_t)(jrow + 16 + r) * N_SAMP + ncol     ] = acc10[r];
        Mt[(size_t)(jrow + 16 + r) * N_SAMP + ncol + 16] = acc11[r];
    }
}

// --- dist stage 1: per-(o, m-chunk) partial sums, no atomics ---
// grid (128 o, 8 chunks) = 1024 blocks (4/CU). 256 thr = 4 waves.
// Wave w handles 8 m's; each lane handles 4 n-rows; k split into 4x8 so the
// live set (~90 VGPR) stays register-resident (r3's VGPR=88 < needed 128+
// showed the 4x32 version was NOT register-resident).
__global__ __launch_bounds__(256) void dist_part(const float* __restrict__ Mt,
                                                 float* __restrict__ part) {
    __shared__ float Mo[MPC][36];        // [m][k], row stride 144 B (16B-aligned)
    __shared__ float Pred[4][N_SAMP];    // per-wave partials
    const int t = threadIdx.x, w = t >> 6, l = t & 63;
    const int o  = blockIdx.x;           // 0..127
    const int mb = blockIdx.y * MPC;     // 0..224

    {   // stage Mo[32][32]: coalesced (lanes = consecutive m)
        const int m = t & 31, kb = (t >> 5) * 4;
#pragma unroll
        for (int kk = 0; kk < 4; ++kk)
            Mo[m][kb + kk] = Mt[(size_t)(o * KDIM + kb + kk) * N_SAMP + mb + m];
    }
    __syncthreads();

    float accd[4][MPW];                  // partial L1 distances [row][m] — 32 chains
#pragma unroll
    for (int r = 0; r < 4; ++r)
#pragma unroll
        for (int m = 0; m < MPW; ++m) accd[r][m] = 0.f;

#pragma unroll
    for (int kh = 0; kh < 4; ++kh) {     // k in 4 chunks of 8
        float r0[8], r1[8], r2[8], r3[8];
#pragma unroll
        for (int k = 0; k < 8; ++k) {    // lane-coalesced column loads
            const float* p = Mt + (size_t)(o * KDIM + kh * 8 + k) * N_SAMP + l;
            r0[k] = p[0]; r1[k] = p[64]; r2[k] = p[128]; r3[k] = p[192];
        }
#pragma unroll
        for (int m = 0; m < MPW; ++m) {
            float mo[8];
#pragma unroll
            for (int i = 0; i < 2; ++i)  // wave-uniform broadcast reads
                *reinterpret_cast<float4*>(&mo[i * 4]) =
                    *reinterpret_cast<const float4*>(&Mo[w * MPW + m][kh * 8 + i * 4]);
#pragma unroll
            for (int k = 0; k < 8; ++k) {
                accd[0][m] += fabsf(r0[k] - mo[k]);
                accd[1][m] += fabsf(r1[k] - mo[k]);
                accd[2][m] += fabsf(r2[k] - mo[k]);
                accd[3][m] += fabsf(r3[k] - mo[k]);
            }
        }
    }

    float a0 = 0.f, a1 = 0.f, a2 = 0.f, a3 = 0.f;
#pragma unroll
    for (int m = 0; m < MPW; ++m) {
        a0 += __expf(-accd[0][m]); a1 += __expf(-accd[1][m]);
        a2 += __expf(-accd[2][m]); a3 += __expf(-accd[3][m]);
    }
    Pred[w][l] = a0; Pred[w][l + 64] = a1; Pred[w][l + 128] = a2; Pred[w][l + 192] = a3;
    __syncthreads();

    {   // sum the 4 waves' m-subranges; coalesced write to part[chunk][o][n]
        float s = Pred[0][t] + Pred[1][t] + Pred[2][t] + Pred[3][t];
        part[(size_t)blockIdx.y * (OUT_F * N_SAMP) + o * N_SAMP + t] = s;
    }
}

// --- dist stage 2: sum 8 chunks, subtract self-term, write out coalesced ---
// grid 256 (=n), 128 thr (=o)
__global__ __launch_bounds__(128) void dist_reduce(const float* __restrict__ part,
                                                   float* __restrict__ out) {
    const int n = blockIdx.x, t = threadIdx.x;
    float s = -1.0f;
#pragma unroll
    for (int c = 0; c < CHUNKS; ++c)
        s += part[(size_t)c * (OUT_F * N_SAMP) + t * N_SAMP + n];
    out[(size_t)n * OUT_ROW + IN_F + t] = s;
}

// ===========================================================================
// FALLBACK PATH (round-1 proven kernels; used only if ws is too small)
// ===========================================================================
__global__ __launch_bounds__(256) void copy_init_kernel(const float* __restrict__ x,
                                                        float* __restrict__ out) {
    int n = blockIdx.x, t = threadIdx.x;
    reinterpret_cast<float4*>(out + (size_t)n * OUT_ROW)[t] =
        reinterpret_cast<const float4*>(x + (size_t)n * IN_F)[t];
    if (t < OUT_F) out[(size_t)n * OUT_ROW + IN_F + t] = -1.0f;
}

#define BM 64
#define BN 64
#define BK 16
#define AS_STRIDE 68
__global__ __launch_bounds__(256) void gemm_kernel(const float* __restrict__ x,
                                                   const float* __restrict__ T,
                                                   float* __restrict__ M) {
    __shared__ float As_[BK][AS_STRIDE];
    __shared__ float Bs_[BK][BN];
    const int jb = blockIdx.x * BN, nb = blockIdx.y * BM;
    const int t = threadIdx.x, tx = t & 15, ty = t >> 4;
    float acc[4][4] = {};
    for (int k0 = 0; k0 < IN_F; k0 += BK) {
        {
            int row = t >> 2, cg = (t & 3) * 4;
            float4 v = *reinterpret_cast<const float4*>(&x[(size_t)(nb + row) * IN_F + k0 + cg]);
            As_[cg + 0][row] = v.x; As_[cg + 1][row] = v.y;
            As_[cg + 2][row] = v.z; As_[cg + 3][row] = v.w;
        }
        {
            int r = t >> 4, cg = (t & 15) * 4;
            *reinterpret_cast<float4*>(&Bs_[r][cg]) =
                *reinterpret_cast<const float4*>(&T[(size_t)(k0 + r) * JTOT + jb + cg]);
        }
        __syncthreads();
#pragma unroll
        for (int kk = 0; kk < BK; ++kk) {
            float4 av = *reinterpret_cast<const float4*>(&As_[kk][ty * 4]);
            float4 bv = *reinterpret_cast<const float4*>(&Bs_[kk][tx * 4]);
            float a[4] = {av.x, av.y, av.z, av.w}, b[4] = {bv.x, bv.y, bv.z, bv.w};
#pragma unroll
            for (int i = 0; i < 4; ++i)
#pragma unroll
                for (int j = 0; j < 4; ++j) acc[i][j] += a[i] * b[j];
        }
        __syncthreads();
    }
#pragma unroll
    for (int i = 0; i < 4; ++i) {
        int n = nb + ty * 4 + i;
        float4 v = make_float4(acc[i][0], acc[i][1], acc[i][2], acc[i][3]);
        *reinterpret_cast<float4*>(&M[(size_t)n * JTOT + jb + tx * 4]) = v;
    }
}

__global__ __launch_bounds__(256) void dist_kernel(const float* __restrict__ M,
                                                   float* __restrict__ out) {
    __shared__ float Mo_[64][KDIM];
    const int o = blockIdx.x >> 2, chunk = blockIdx.x & 3, t = threadIdx.x;
    float r[KDIM];
    const float4* mrow = reinterpret_cast<const float4*>(&M[(size_t)t * JTOT + o * KDIM]);
#pragma unroll
    for (int f = 0; f < 8; ++f) {
        float4 v = mrow[f];
        r[f*4+0]=v.x; r[f*4+1]=v.y; r[f*4+2]=v.z; r[f*4+3]=v.w;
    }
    const int mbase = chunk * 64;
    {
        int row = t >> 3, f4 = t & 7;
        *reinterpret_cast<float4*>(&Mo_[row][f4*4]) =
            *reinterpret_cast<const float4*>(&M[(size_t)(mbase+row)*JTOT + o*KDIM + f4*4]);
        *reinterpret_cast<float4*>(&Mo_[row+32][f4*4]) =
            *reinterpret_cast<const float4*>(&M[(size_t)(mbase+row+32)*JTOT + o*KDIM + f4*4]);
    }
    __syncthreads();
    float acc = 0.f;
    for (int m = 0; m < 64; ++m) {
        float d = 0.f;
#pragma unroll
        for (int k = 0; k < KDIM; ++k) d += fabsf(r[k] - Mo_[m][k]);
        acc += __expf(-d);
    }
    atomicAdd(&out[(size_t)t * OUT_ROW + IN_F + o], acc);
}

// ===========================================================================
extern "C" void kernel_launch(void* const* d_in, const int* in_sizes, int n_in,
                              void* d_out, int out_size, void* d_ws, size_t ws_size,
                              hipStream_t stream) {
    const float* x = (const float*)d_in[0];   // [256,1024]
    const float* T = (const float*)d_in[1];   // [1024,4096]
    float* out = (float*)d_out;               // [256,1152]

    const size_t MT_BYTES = (size_t)JTOT * N_SAMP * 4;        // 4 MiB
    const size_t AT_BYTES = (size_t)N_SAMP * IN_F * 2;        // 0.5 MiB
    const size_t BT_BYTES = (size_t)JTOT * IN_F * 2;          // 8 MiB

    if (ws_size >= MT_BYTES + AT_BYTES + BT_BYTES) {
        float* Mt = (float*)d_ws;
        u16*   At = (u16*)((char*)d_ws + MT_BYTES);
        u16*   Bt = (u16*)((char*)d_ws + MT_BYTES + AT_BYTES);
        // part (1 MiB) aliases the Bt region: Bt is dead once mfma_gemm ends,
        // and dist_part runs after it (stream-ordered), so no hazard.
        float* part = (float*)Bt;

        copy_init_conv<<<N_SAMP, 256, 0, stream>>>(x, out, At);
        convT_kernel<<<dim3(JTOT / 64, IN_F / 64), 256, 0, stream>>>(T, Bt);
        mfma_gemm<<<dim3(JTOT / 64, N_SAMP / 32), 128, 0, stream>>>(At, Bt, Mt);
        dist_part<<<dim3(OUT_F, CHUNKS), 256, 0, stream>>>(Mt, part);
        dist_reduce<<<N_SAMP, 128, 0, stream>>>(part, out);
    } else {
        float* M = (float*)d_ws;              // 4 MiB (proven available in r1)
        copy_init_kernel<<<N_SAMP, 256, 0, stream>>>(x, out);
        dim3 ggrid(JTOT / BN, N_SAMP / BM);
        gemm_kernel<<<ggrid, 256, 0, stream>>>(x, T, M);
        dist_kernel<<<OUT_F * 4, 256, 0, stream>>>(M, out);
    }
}

// Round 6
// 117.801 us; speedup vs baseline: 1.3060x; 1.0225x over previous
//
#include <hip/hip_runtime.h>

typedef unsigned short u16;
typedef __attribute__((ext_vector_type(8))) short short8_t;   // 8 bf16 = 4 VGPRs
typedef __attribute__((ext_vector_type(4))) float f32x4;      // MFMA accumulator

#define N_SAMP 256
#define IN_F   1024
#define OUT_F  128
#define KDIM   32
#define JTOT   (OUT_F * KDIM)   // 4096
#define OUT_ROW (IN_F + OUT_F)  // 1152

#define CHUNKS 8                 // m-chunks for dist partials
#define MPC    32                // m per chunk (per block)
#define MPW    8                 // m per wave

__device__ __forceinline__ u16 f2bf(float f) {
    union { float f; unsigned u; } v; v.f = f;
    unsigned r = v.u + 0x7FFFu + ((v.u >> 16) & 1u);   // RNE
    return (u16)(r >> 16);
}

// ===========================================================================
// MAIN PATH
// ===========================================================================

// --- prep: T[k][j] fp32 -> Bt[j][k] bf16 (tiled transpose), and for the
// first 256 blocks also: x -> out[:, :1024] copy + x -> bf16 At[n][k].
// grid dim3(64, 16) = 1024 blocks, 256 thr.
__global__ __launch_bounds__(256) void prep_kernel(const float* __restrict__ x,
                                                   const float* __restrict__ T,
                                                   float* __restrict__ out,
                                                   u16* __restrict__ At,
                                                   u16* __restrict__ Bt) {
    __shared__ float Ls[64 * 65];                 // odd stride -> conflict-light
    const int t = threadIdx.x;
    const int j0 = blockIdx.x * 64, k0 = blockIdx.y * 64;
    const int r = t >> 2, c4 = t & 3;

    const float4* src = reinterpret_cast<const float4*>(T + (size_t)(k0 + r) * JTOT + j0 + c4 * 16);
    float4 v0 = src[0], v1 = src[1], v2 = src[2], v3 = src[3];
    float vv[16] = {v0.x,v0.y,v0.z,v0.w, v1.x,v1.y,v1.z,v1.w,
                    v2.x,v2.y,v2.z,v2.w, v3.x,v3.y,v3.z,v3.w};
#pragma unroll
    for (int i = 0; i < 16; ++i) Ls[r * 65 + c4 * 16 + i] = vv[i];
    __syncthreads();

    unsigned pk[8];
#pragma unroll
    for (int i = 0; i < 8; ++i) {
        u16 lo = f2bf(Ls[(c4 * 16 + 2 * i    ) * 65 + r]);
        u16 hi = f2bf(Ls[(c4 * 16 + 2 * i + 1) * 65 + r]);
        pk[i] = (unsigned)lo | ((unsigned)hi << 16);
    }
    uint4* dst = reinterpret_cast<uint4*>(Bt + (size_t)(j0 + r) * IN_F + k0 + c4 * 16);
    dst[0] = make_uint4(pk[0], pk[1], pk[2], pk[3]);
    dst[1] = make_uint4(pk[4], pk[5], pk[6], pk[7]);

    // fused x-copy/convert for the first 256 blocks (one n-row each)
    const int bid = blockIdx.y * 64 + blockIdx.x;
    if (bid < N_SAMP) {
        float4 v = reinterpret_cast<const float4*>(x + (size_t)bid * IN_F)[t];
        reinterpret_cast<float4*>(out + (size_t)bid * OUT_ROW)[t] = v;
        ushort4 b;
        b.x = f2bf(v.x); b.y = f2bf(v.y); b.z = f2bf(v.z); b.w = f2bf(v.w);
        reinterpret_cast<ushort4*>(At + (size_t)bid * IN_F)[t] = b;
    }
}

// --- Mt[4096][256] = Bt[4096][1024] x At[256][1024]^T via 16x16x32 bf16 MFMA ---
// Double-buffered LDS, ONE barrier per K-step (was 2). 128 thr = 2 waves.
// tile 64j x 32n; grid (64, 8) = 512 blocks.
#define LDB 136   // 128 + 8 bf16 pad: row stride 272 B (16B-unit step 17 -> 2-way max)
__global__ __launch_bounds__(128) void mfma_gemm(const u16* __restrict__ At,
                                                 const u16* __restrict__ Bt,
                                                 float* __restrict__ Mt) {
    __shared__ u16 Bs[2][64 * LDB];   // 2 x 17408 B
    __shared__ u16 As[2][32 * LDB];   // 2 x  8704 B   (total 52224 B)
    const int t = threadIdx.x;
    const int w = t >> 6, l = t & 63;
    const int jb = blockIdx.x * 64, nb = blockIdx.y * 32;
    const int rb = t >> 1, hb = t & 1;   // Bt staging: row (0..63), k-half
    const int ra = t >> 2, qa = t & 3;   // At staging: row (0..31), k-quarter

    f32x4 acc00 = {0.f,0.f,0.f,0.f}, acc01 = {0.f,0.f,0.f,0.f};
    f32x4 acc10 = {0.f,0.f,0.f,0.f}, acc11 = {0.f,0.f,0.f,0.f};

    float4 sb[8], sa[4];
    auto LOADG = [&](int it) {
        const float4* gb = reinterpret_cast<const float4*>(Bt + (size_t)(jb + rb) * IN_F + it * 128 + hb * 64);
#pragma unroll
        for (int i = 0; i < 8; ++i) sb[i] = gb[i];
        const float4* ga = reinterpret_cast<const float4*>(At + (size_t)(nb + ra) * IN_F + it * 128 + qa * 32);
#pragma unroll
        for (int i = 0; i < 4; ++i) sa[i] = ga[i];
    };
    auto STORE = [&](int b) {
#pragma unroll
        for (int i = 0; i < 8; ++i) *reinterpret_cast<float4*>(&Bs[b][rb * LDB + hb * 64 + i * 8]) = sb[i];
#pragma unroll
        for (int i = 0; i < 4; ++i) *reinterpret_cast<float4*>(&As[b][ra * LDB + qa * 32 + i * 8]) = sa[i];
    };

    LOADG(0); STORE(0); __syncthreads();

#pragma unroll 2
    for (int it = 0; it < 8; ++it) {
        const int cur = it & 1;
        if (it < 7) LOADG(it + 1);          // issue next tile's loads early
#pragma unroll
        for (int s = 0; s < 4; ++s) {
            const int co = s * 32 + 8 * (l >> 4);     // same assumed k-map for A and B
            short8_t a0 = *reinterpret_cast<const short8_t*>(&Bs[cur][(w * 32 +      (l & 15)) * LDB + co]);
            short8_t a1 = *reinterpret_cast<const short8_t*>(&Bs[cur][(w * 32 + 16 + (l & 15)) * LDB + co]);
            short8_t b0 = *reinterpret_cast<const short8_t*>(&As[cur][(          (l & 15)) * LDB + co]);
            short8_t b1 = *reinterpret_cast<const short8_t*>(&As[cur][(     16 + (l & 15)) * LDB + co]);
            acc00 = __builtin_amdgcn_mfma_f32_16x16x32_bf16(a0, b0, acc00, 0, 0, 0);
            acc01 = __builtin_amdgcn_mfma_f32_16x16x32_bf16(a0, b1, acc01, 0, 0, 0);
            acc10 = __builtin_amdgcn_mfma_f32_16x16x32_bf16(a1, b0, acc10, 0, 0, 0);
            acc11 = __builtin_amdgcn_mfma_f32_16x16x32_bf16(a1, b1, acc11, 0, 0, 0);
        }
        if (it < 7) STORE((it + 1) & 1);    // write OTHER buffer: no read hazard
        __syncthreads();                    // single barrier per K-step
    }

    // C/D layout (m89-verified): col = lane&15 (n-index), row = 4*(lane>>4)+reg (j-index)
    const int jrow = jb + w * 32 + (l >> 4) * 4;
    const int ncol = nb + (l & 15);
#pragma unroll
    for (int r = 0; r < 4; ++r) {
        Mt[(size_t)(jrow + r     ) * N_SAMP + ncol     ] = acc00[r];
        Mt[(size_t)(jrow + r     ) * N_SAMP + ncol + 16] = acc01[r];
        Mt[(size_t)(jrow + 16 + r) * N_SAMP + ncol     ] = acc10[r];
        Mt[(size_t)(jrow + 16 + r) * N_SAMP + ncol + 16] = acc11[r];
    }
}

// --- dist stage 1: per-(o, m-chunk) partial sums, no atomics (UNCHANGED) ---
__global__ __launch_bounds__(256) void dist_part(const float* __restrict__ Mt,
                                                 float* __restrict__ part) {
    __shared__ float Mo[MPC][36];        // [m][k], row stride 144 B (16B-aligned)
    __shared__ float Pred[4][N_SAMP];    // per-wave partials
    const int t = threadIdx.x, w = t >> 6, l = t & 63;
    const int o  = blockIdx.x;           // 0..127
    const int mb = blockIdx.y * MPC;     // 0..224

    {   // stage Mo[32][32]: coalesced (lanes = consecutive m)
        const int m = t & 31, kb = (t >> 5) * 4;
#pragma unroll
        for (int kk = 0; kk < 4; ++kk)
            Mo[m][kb + kk] = Mt[(size_t)(o * KDIM + kb + kk) * N_SAMP + mb + m];
    }
    __syncthreads();

    float accd[4][MPW];                  // partial L1 distances [row][m] — 32 chains
#pragma unroll
    for (int r = 0; r < 4; ++r)
#pragma unroll
        for (int m = 0; m < MPW; ++m) accd[r][m] = 0.f;

#pragma unroll
    for (int kh = 0; kh < 4; ++kh) {     // k in 4 chunks of 8
        float r0[8], r1[8], r2[8], r3[8];
#pragma unroll
        for (int k = 0; k < 8; ++k) {    // lane-coalesced column loads
            const float* p = Mt + (size_t)(o * KDIM + kh * 8 + k) * N_SAMP + l;
            r0[k] = p[0]; r1[k] = p[64]; r2[k] = p[128]; r3[k] = p[192];
        }
#pragma unroll
        for (int m = 0; m < MPW; ++m) {
            float mo[8];
#pragma unroll
            for (int i = 0; i < 2; ++i)  // wave-uniform broadcast reads
                *reinterpret_cast<float4*>(&mo[i * 4]) =
                    *reinterpret_cast<const float4*>(&Mo[w * MPW + m][kh * 8 + i * 4]);
#pragma unroll
            for (int k = 0; k < 8; ++k) {
                accd[0][m] += fabsf(r0[k] - mo[k]);
                accd[1][m] += fabsf(r1[k] - mo[k]);
                accd[2][m] += fabsf(r2[k] - mo[k]);
                accd[3][m] += fabsf(r3[k] - mo[k]);
            }
        }
    }

    float a0 = 0.f, a1 = 0.f, a2 = 0.f, a3 = 0.f;
#pragma unroll
    for (int m = 0; m < MPW; ++m) {
        a0 += __expf(-accd[0][m]); a1 += __expf(-accd[1][m]);
        a2 += __expf(-accd[2][m]); a3 += __expf(-accd[3][m]);
    }
    Pred[w][l] = a0; Pred[w][l + 64] = a1; Pred[w][l + 128] = a2; Pred[w][l + 192] = a3;
    __syncthreads();

    {   // sum the 4 waves' m-subranges; coalesced write to part[chunk][o][n]
        float s = Pred[0][t] + Pred[1][t] + Pred[2][t] + Pred[3][t];
        part[(size_t)blockIdx.y * (OUT_F * N_SAMP) + o * N_SAMP + t] = s;
    }
}

// --- dist stage 2: sum 8 chunks, subtract self-term ---
// grid 128 (=o), 256 thr (=n): part[c][o][n] reads now CONTIGUOUS per wave.
__global__ __launch_bounds__(256) void dist_reduce(const float* __restrict__ part,
                                                   float* __restrict__ out) {
    const int o = blockIdx.x, n = threadIdx.x;
    float s = -1.0f;
#pragma unroll
    for (int c = 0; c < CHUNKS; ++c)
        s += part[(size_t)c * (OUT_F * N_SAMP) + o * N_SAMP + n];
    out[(size_t)n * OUT_ROW + IN_F + o] = s;
}

// ===========================================================================
// FALLBACK PATH (round-1 proven kernels; used only if ws is too small)
// ===========================================================================
__global__ __launch_bounds__(256) void copy_init_kernel(const float* __restrict__ x,
                                                        float* __restrict__ out) {
    int n = blockIdx.x, t = threadIdx.x;
    reinterpret_cast<float4*>(out + (size_t)n * OUT_ROW)[t] =
        reinterpret_cast<const float4*>(x + (size_t)n * IN_F)[t];
    if (t < OUT_F) out[(size_t)n * OUT_ROW + IN_F + t] = -1.0f;
}

#define BM 64
#define BN 64
#define BK 16
#define AS_STRIDE 68
__global__ __launch_bounds__(256) void gemm_kernel(const float* __restrict__ x,
                                                   const float* __restrict__ T,
                                                   float* __restrict__ M) {
    __shared__ float As_[BK][AS_STRIDE];
    __shared__ float Bs_[BK][BN];
    const int jb = blockIdx.x * BN, nb = blockIdx.y * BM;
    const int t = threadIdx.x, tx = t & 15, ty = t >> 4;
    float acc[4][4] = {};
    for (int k0 = 0; k0 < IN_F; k0 += BK) {
        {
            int row = t >> 2, cg = (t & 3) * 4;
            float4 v = *reinterpret_cast<const float4*>(&x[(size_t)(nb + row) * IN_F + k0 + cg]);
            As_[cg + 0][row] = v.x; As_[cg + 1][row] = v.y;
            As_[cg + 2][row] = v.z; As_[cg + 3][row] = v.w;
        }
        {
            int r = t >> 4, cg = (t & 15) * 4;
            *reinterpret_cast<float4*>(&Bs_[r][cg]) =
                *reinterpret_cast<const float4*>(&T[(size_t)(k0 + r) * JTOT + jb + cg]);
        }
        __syncthreads();
#pragma unroll
        for (int kk = 0; kk < BK; ++kk) {
            float4 av = *reinterpret_cast<const float4*>(&As_[kk][ty * 4]);
            float4 bv = *reinterpret_cast<const float4*>(&Bs_[kk][tx * 4]);
            float a[4] = {av.x, av.y, av.z, av.w}, b[4] = {bv.x, bv.y, bv.z, bv.w};
#pragma unroll
            for (int i = 0; i < 4; ++i)
#pragma unroll
                for (int j = 0; j < 4; ++j) acc[i][j] += a[i] * b[j];
        }
        __syncthreads();
    }
#pragma unroll
    for (int i = 0; i < 4; ++i) {
        int n = nb + ty * 4 + i;
        float4 v = make_float4(acc[i][0], acc[i][1], acc[i][2], acc[i][3]);
        *reinterpret_cast<float4*>(&M[(size_t)n * JTOT + jb + tx * 4]) = v;
    }
}

__global__ __launch_bounds__(256) void dist_kernel(const float* __restrict__ M,
                                                   float* __restrict__ out) {
    __shared__ float Mo_[64][KDIM];
    const int o = blockIdx.x >> 2, chunk = blockIdx.x & 3, t = threadIdx.x;
    float r[KDIM];
    const float4* mrow = reinterpret_cast<const float4*>(&M[(size_t)t * JTOT + o * KDIM]);
#pragma unroll
    for (int f = 0; f < 8; ++f) {
        float4 v = mrow[f];
        r[f*4+0]=v.x; r[f*4+1]=v.y; r[f*4+2]=v.z; r[f*4+3]=v.w;
    }
    const int mbase = chunk * 64;
    {
        int row = t >> 3, f4 = t & 7;
        *reinterpret_cast<float4*>(&Mo_[row][f4*4]) =
            *reinterpret_cast<const float4*>(&M[(size_t)(mbase+row)*JTOT + o*KDIM + f4*4]);
        *reinterpret_cast<float4*>(&Mo_[row+32][f4*4]) =
            *reinterpret_cast<const float4*>(&M[(size_t)(mbase+row+32)*JTOT + o*KDIM + f4*4]);
    }
    __syncthreads();
    float acc = 0.f;
    for (int m = 0; m < 64; ++m) {
        float d = 0.f;
#pragma unroll
        for (int k = 0; k < KDIM; ++k) d += fabsf(r[k] - Mo_[m][k]);
        acc += __expf(-d);
    }
    atomicAdd(&out[(size_t)t * OUT_ROW + IN_F + o], acc);
}

// ===========================================================================
extern "C" void kernel_launch(void* const* d_in, const int* in_sizes, int n_in,
                              void* d_out, int out_size, void* d_ws, size_t ws_size,
                              hipStream_t stream) {
    const float* x = (const float*)d_in[0];   // [256,1024]
    const float* T = (const float*)d_in[1];   // [1024,4096]
    float* out = (float*)d_out;               // [256,1152]

    const size_t MT_BYTES = (size_t)JTOT * N_SAMP * 4;        // 4 MiB
    const size_t AT_BYTES = (size_t)N_SAMP * IN_F * 2;        // 0.5 MiB
    const size_t BT_BYTES = (size_t)JTOT * IN_F * 2;          // 8 MiB

    if (ws_size >= MT_BYTES + AT_BYTES + BT_BYTES) {
        float* Mt = (float*)d_ws;
        u16*   At = (u16*)((char*)d_ws + MT_BYTES);
        u16*   Bt = (u16*)((char*)d_ws + MT_BYTES + AT_BYTES);
        // part (1 MiB) aliases the Bt region: Bt is dead once mfma_gemm ends,
        // and dist_part runs after it (stream-ordered), so no hazard.
        float* part = (float*)Bt;

        prep_kernel<<<dim3(JTOT / 64, IN_F / 64), 256, 0, stream>>>(x, T, out, At, Bt);
        mfma_gemm<<<dim3(JTOT / 64, N_SAMP / 32), 128, 0, stream>>>(At, Bt, Mt);
        dist_part<<<dim3(OUT_F, CHUNKS), 256, 0, stream>>>(Mt, part);
        dist_reduce<<<OUT_F, 256, 0, stream>>>(part, out);
    } else {
        float* M = (float*)d_ws;              // 4 MiB (proven available in r1)
        copy_init_kernel<<<N_SAMP, 256, 0, stream>>>(x, out);
        dim3 ggrid(JTOT / BN, N_SAMP / BM);
        gemm_kernel<<<ggrid, 256, 0, stream>>>(x, T, M);
        dist_kernel<<<OUT_F * 4, 256, 0, stream>>>(M, out);
    }
}

// Round 11
// 103.353 us; speedup vs baseline: 1.4886x; 1.1398x over previous
//
#include <hip/hip_runtime.h>

typedef unsigned short u16;
typedef __attribute__((ext_vector_type(8))) short short8_t;   // 8 bf16 = 4 VGPRs
typedef __attribute__((ext_vector_type(4))) float f32x4;      // MFMA accumulator

#define N_SAMP 256
#define IN_F   1024
#define OUT_F  128
#define KDIM   32
#define JTOT   (OUT_F * KDIM)   // 4096
#define OUT_ROW (IN_F + OUT_F)  // 1152
#define MT_ELEMS ((size_t)JTOT * N_SAMP)   // one Mt half: 1M floats = 4 MiB

#define CHUNKS 8                 // m-chunks for dist partials
#define MPC    32                // m per chunk (per block)
#define MPW    8                 // m per wave

__device__ __forceinline__ u16 f2bf(float f) {
    union { float f; unsigned u; } v; v.f = f;
    unsigned r = v.u + 0x7FFFu + ((v.u >> 16) & 1u);   // RNE
    return (u16)(r >> 16);
}

// ===========================================================================
// MAIN PATH: fused convert+transpose+GEMM (split-K), then dist.
// Mt halves: Mt[kz][j][n], kz in {0,1}; dist sums the halves on read.
// ===========================================================================

// grid (64 j, 4 n, 2 kz) = 512 blocks, 256 thr = 4 waves (2j x 2n quadrants).
// Block tile: 64j x 64n x 512k; per wave 32j x 32n. K-step 128, dbuf LDS.
#define LDB 136   // 128 bf16 + 8 pad: row stride 272 B (16B-aligned)
__global__ __launch_bounds__(256) void gemm_fused(const float* __restrict__ x,
                                                  const float* __restrict__ T,
                                                  float* __restrict__ out,
                                                  float* __restrict__ Mt) {
    __shared__ u16 Bs[2][64 * LDB];   // j rows (transposed from T)  2 x 17408 B
    __shared__ u16 As[2][64 * LDB];   // n rows (from x)             2 x 17408 B
    const int t = threadIdx.x, w = t >> 6, l = t & 63;
    const int wr = (w >> 1) * 32, wc = (w & 1) * 32;   // wave quadrant offsets
    const int jb = blockIdx.x * 64, nb = blockIdx.y * 64;
    const int kbase = blockIdx.z * 512;
    float* Mth = Mt + (size_t)blockIdx.z * MT_ELEMS;

    // fused x -> out[:, :1024] copy (64 blocks of the kz=0 plane, 4 rows each)
    if (blockIdx.z == 0 && blockIdx.x < 16) {
        const int row = nb + blockIdx.x * 4 + (t >> 6);
        const float4* src = reinterpret_cast<const float4*>(x + (size_t)row * IN_F);
        float4* dst = reinterpret_cast<float4*>(out + (size_t)row * OUT_ROW);
#pragma unroll
        for (int i = 0; i < 4; ++i) dst[(t & 63) + 64 * i] = src[(t & 63) + 64 * i];
    }

    const int kp = t >> 2;           // T: k-pair 0..63   | x: n-row 0..63
    const int q  = t & 3;            // T: j-quad (16 j)  | x: k-quad (32 k)

    f32x4 acc00 = {0.f,0.f,0.f,0.f}, acc01 = {0.f,0.f,0.f,0.f};
    f32x4 acc10 = {0.f,0.f,0.f,0.f}, acc11 = {0.f,0.f,0.f,0.f};

    float4 ta[4], tb[4], xv[8];      // staging registers (16 float4)
    auto LOADG = [&](int it) {
        const int k0 = kbase + it * 128;
        const float4* gT0 = reinterpret_cast<const float4*>(T + (size_t)(k0 + 2 * kp    ) * JTOT + jb + q * 16);
        const float4* gT1 = reinterpret_cast<const float4*>(T + (size_t)(k0 + 2 * kp + 1) * JTOT + jb + q * 16);
#pragma unroll
        for (int i = 0; i < 4; ++i) { ta[i] = gT0[i]; tb[i] = gT1[i]; }
        const float4* gx = reinterpret_cast<const float4*>(x + (size_t)(nb + kp) * IN_F + k0 + q * 32);
#pragma unroll
        for (int i = 0; i < 8; ++i) xv[i] = gx[i];
    };
    auto STORE = [&](int b) {
        // T-part: transpose-write. Bs[j][k] bf16, k-pairs packed as u32.
#pragma unroll
        for (int i = 0; i < 4; ++i) {
            const float* fa = reinterpret_cast<const float*>(&ta[i]);
            const float* fb = reinterpret_cast<const float*>(&tb[i]);
#pragma unroll
            for (int c = 0; c < 4; ++c) {
                unsigned v = (unsigned)f2bf(fa[c]) | ((unsigned)f2bf(fb[c]) << 16);
                *reinterpret_cast<unsigned*>(&Bs[b][(q * 16 + i * 4 + c) * LDB + 2 * kp]) = v;
            }
        }
        // x-part: k-linear, vector writes.
#pragma unroll
        for (int i = 0; i < 4; ++i) {
            const float* f0 = reinterpret_cast<const float*>(&xv[2 * i]);
            const float* f1 = reinterpret_cast<const float*>(&xv[2 * i + 1]);
            uint4 pv;
            pv.x = (unsigned)f2bf(f0[0]) | ((unsigned)f2bf(f0[1]) << 16);
            pv.y = (unsigned)f2bf(f0[2]) | ((unsigned)f2bf(f0[3]) << 16);
            pv.z = (unsigned)f2bf(f1[0]) | ((unsigned)f2bf(f1[1]) << 16);
            pv.w = (unsigned)f2bf(f1[2]) | ((unsigned)f2bf(f1[3]) << 16);
            *reinterpret_cast<uint4*>(&As[b][kp * LDB + q * 32 + i * 8]) = pv;
        }
    };

    LOADG(0); STORE(0); __syncthreads();

    for (int it = 0; it < 4; ++it) {
        const int cur = it & 1;
        if (it < 3) LOADG(it + 1);          // next tile's global loads early
#pragma unroll
        for (int s = 0; s < 4; ++s) {
            const int co = s * 32 + 8 * (l >> 4);     // same assumed k-map A and B
            short8_t a0 = *reinterpret_cast<const short8_t*>(&Bs[cur][(wr +      (l & 15)) * LDB + co]);
            short8_t a1 = *reinterpret_cast<const short8_t*>(&Bs[cur][(wr + 16 + (l & 15)) * LDB + co]);
            short8_t b0 = *reinterpret_cast<const short8_t*>(&As[cur][(wc +      (l & 15)) * LDB + co]);
            short8_t b1 = *reinterpret_cast<const short8_t*>(&As[cur][(wc + 16 + (l & 15)) * LDB + co]);
            acc00 = __builtin_amdgcn_mfma_f32_16x16x32_bf16(a0, b0, acc00, 0, 0, 0);
            acc01 = __builtin_amdgcn_mfma_f32_16x16x32_bf16(a0, b1, acc01, 0, 0, 0);
            acc10 = __builtin_amdgcn_mfma_f32_16x16x32_bf16(a1, b0, acc10, 0, 0, 0);
            acc11 = __builtin_amdgcn_mfma_f32_16x16x32_bf16(a1, b1, acc11, 0, 0, 0);
        }
        if (it < 3) STORE(cur ^ 1);         // write OTHER buffer: no read hazard
        __syncthreads();                    // single barrier per K-step (r5-proven)
    }

    // C/D layout (m89-verified): col = lane&15 (n), row = 4*(lane>>4)+reg (j)
    const int jrow = jb + wr + (l >> 4) * 4;
    const int ncol = nb + wc + (l & 15);
#pragma unroll
    for (int r = 0; r < 4; ++r) {
        Mth[(size_t)(jrow + r     ) * N_SAMP + ncol     ] = acc00[r];
        Mth[(size_t)(jrow + r     ) * N_SAMP + ncol + 16] = acc01[r];
        Mth[(size_t)(jrow + 16 + r) * N_SAMP + ncol     ] = acc10[r];
        Mth[(size_t)(jrow + 16 + r) * N_SAMP + ncol + 16] = acc11[r];
    }
}

// --- dist stage 1: per-(o, m-chunk) partials; sums the two Mt halves on read ---
__global__ __launch_bounds__(256) void dist_part(const float* __restrict__ Mt,
                                                 float* __restrict__ part) {
    __shared__ float Mo[MPC][36];        // [m][k], row stride 144 B
    __shared__ float Pred[4][N_SAMP];    // per-wave partials
    const int t = threadIdx.x, w = t >> 6, l = t & 63;
    const int o  = blockIdx.x;           // 0..127
    const int mb = blockIdx.y * MPC;     // 0..224
    const float* Mt1 = Mt + MT_ELEMS;

    {   // stage Mo[32][32]: coalesced (lanes = consecutive m), halves summed
        const int m = t & 31, kb = (t >> 5) * 4;
#pragma unroll
        for (int kk = 0; kk < 4; ++kk) {
            size_t idx = (size_t)(o * KDIM + kb + kk) * N_SAMP + mb + m;
            Mo[m][kb + kk] = Mt[idx] + Mt1[idx];
        }
    }
    __syncthreads();

    float accd[4][MPW];                  // partial L1 distances [row][m]
#pragma unroll
    for (int r = 0; r < 4; ++r)
#pragma unroll
        for (int m = 0; m < MPW; ++m) accd[r][m] = 0.f;

#pragma unroll
    for (int kh = 0; kh < 4; ++kh) {     // k in 4 chunks of 8
        float r0[8], r1[8], r2[8], r3[8];
#pragma unroll
        for (int k = 0; k < 8; ++k) {    // lane-coalesced column loads, halves summed
            const size_t off = (size_t)(o * KDIM + kh * 8 + k) * N_SAMP + l;
            const float* p0 = Mt  + off;
            const float* p1 = Mt1 + off;
            r0[k] = p0[0]   + p1[0];
            r1[k] = p0[64]  + p1[64];
            r2[k] = p0[128] + p1[128];
            r3[k] = p0[192] + p1[192];
        }
#pragma unroll
        for (int m = 0; m < MPW; ++m) {
            float mo[8];
#pragma unroll
            for (int i = 0; i < 2; ++i)  // wave-uniform broadcast reads
                *reinterpret_cast<float4*>(&mo[i * 4]) =
                    *reinterpret_cast<const float4*>(&Mo[w * MPW + m][kh * 8 + i * 4]);
#pragma unroll
            for (int k = 0; k < 8; ++k) {
                accd[0][m] += fabsf(r0[k] - mo[k]);
                accd[1][m] += fabsf(r1[k] - mo[k]);
                accd[2][m] += fabsf(r2[k] - mo[k]);
                accd[3][m] += fabsf(r3[k] - mo[k]);
            }
        }
    }

    float a0 = 0.f, a1 = 0.f, a2 = 0.f, a3 = 0.f;
#pragma unroll
    for (int m = 0; m < MPW; ++m) {
        a0 += __expf(-accd[0][m]); a1 += __expf(-accd[1][m]);
        a2 += __expf(-accd[2][m]); a3 += __expf(-accd[3][m]);
    }
    Pred[w][l] = a0; Pred[w][l + 64] = a1; Pred[w][l + 128] = a2; Pred[w][l + 192] = a3;
    __syncthreads();

    {   // sum the 4 waves' m-subranges; coalesced write to part[chunk][o][n]
        float s = Pred[0][t] + Pred[1][t] + Pred[2][t] + Pred[3][t];
        part[(size_t)blockIdx.y * (OUT_F * N_SAMP) + o * N_SAMP + t] = s;
    }
}

// --- dist stage 2: sum 8 chunks, subtract self-term ---
__global__ __launch_bounds__(256) void dist_reduce(const float* __restrict__ part,
                                                   float* __restrict__ out) {
    const int o = blockIdx.x, n = threadIdx.x;
    float s = -1.0f;
#pragma unroll
    for (int c = 0; c < CHUNKS; ++c)
        s += part[(size_t)c * (OUT_F * N_SAMP) + o * N_SAMP + n];
    out[(size_t)n * OUT_ROW + IN_F + o] = s;
}

// ===========================================================================
// FALLBACK PATH (round-1 proven kernels; used only if ws is too small)
// ===========================================================================
__global__ __launch_bounds__(256) void copy_init_kernel(const float* __restrict__ x,
                                                        float* __restrict__ out) {
    int n = blockIdx.x, t = threadIdx.x;
    reinterpret_cast<float4*>(out + (size_t)n * OUT_ROW)[t] =
        reinterpret_cast<const float4*>(x + (size_t)n * IN_F)[t];
    if (t < OUT_F) out[(size_t)n * OUT_ROW + IN_F + t] = -1.0f;
}

#define BM 64
#define BN 64
#define BK 16
#define AS_STRIDE 68
__global__ __launch_bounds__(256) void gemm_kernel(const float* __restrict__ x,
                                                   const float* __restrict__ T,
                                                   float* __restrict__ M) {
    __shared__ float As_[BK][AS_STRIDE];
    __shared__ float Bs_[BK][BN];
    const int jb = blockIdx.x * BN, nb = blockIdx.y * BM;
    const int t = threadIdx.x, tx = t & 15, ty = t >> 4;
    float acc[4][4] = {};
    for (int k0 = 0; k0 < IN_F; k0 += BK) {
        {
            int row = t >> 2, cg = (t & 3) * 4;
            float4 v = *reinterpret_cast<const float4*>(&x[(size_t)(nb + row) * IN_F + k0 + cg]);
            As_[cg + 0][row] = v.x; As_[cg + 1][row] = v.y;
            As_[cg + 2][row] = v.z; As_[cg + 3][row] = v.w;
        }
        {
            int r = t >> 4, cg = (t & 15) * 4;
            *reinterpret_cast<float4*>(&Bs_[r][cg]) =
                *reinterpret_cast<const float4*>(&T[(size_t)(k0 + r) * JTOT + jb + cg]);
        }
        __syncthreads();
#pragma unroll
        for (int kk = 0; kk < BK; ++kk) {
            float4 av = *reinterpret_cast<const float4*>(&As_[kk][ty * 4]);
            float4 bv = *reinterpret_cast<const float4*>(&Bs_[kk][tx * 4]);
            float a[4] = {av.x, av.y, av.z, av.w}, b[4] = {bv.x, bv.y, bv.z, bv.w};
#pragma unroll
            for (int i = 0; i < 4; ++i)
#pragma unroll
                for (int j = 0; j < 4; ++j) acc[i][j] += a[i] * b[j];
        }
        __syncthreads();
    }
#pragma unroll
    for (int i = 0; i < 4; ++i) {
        int n = nb + ty * 4 + i;
        float4 v = make_float4(acc[i][0], acc[i][1], acc[i][2], acc[i][3]);
        *reinterpret_cast<float4*>(&M[(size_t)n * JTOT + jb + tx * 4]) = v;
    }
}

__global__ __launch_bounds__(256) void dist_kernel(const float* __restrict__ M,
                                                   float* __restrict__ out) {
    __shared__ float Mo_[64][KDIM];
    const int o = blockIdx.x >> 2, chunk = blockIdx.x & 3, t = threadIdx.x;
    float r[KDIM];
    const float4* mrow = reinterpret_cast<const float4*>(&M[(size_t)t * JTOT + o * KDIM]);
#pragma unroll
    for (int f = 0; f < 8; ++f) {
        float4 v = mrow[f];
        r[f*4+0]=v.x; r[f*4+1]=v.y; r[f*4+2]=v.z; r[f*4+3]=v.w;
    }
    const int mbase = chunk * 64;
    {
        int row = t >> 3, f4 = t & 7;
        *reinterpret_cast<float4*>(&Mo_[row][f4*4]) =
            *reinterpret_cast<const float4*>(&M[(size_t)(mbase+row)*JTOT + o*KDIM + f4*4]);
        *reinterpret_cast<float4*>(&Mo_[row+32][f4*4]) =
            *reinterpret_cast<const float4*>(&M[(size_t)(mbase+row+32)*JTOT + o*KDIM + f4*4]);
    }
    __syncthreads();
    float acc = 0.f;
    for (int m = 0; m < 64; ++m) {
        float d = 0.f;
#pragma unroll
        for (int k = 0; k < KDIM; ++k) d += fabsf(r[k] - Mo_[m][k]);
        acc += __expf(-d);
    }
    atomicAdd(&out[(size_t)t * OUT_ROW + IN_F + o], acc);
}

// ===========================================================================
extern "C" void kernel_launch(void* const* d_in, const int* in_sizes, int n_in,
                              void* d_out, int out_size, void* d_ws, size_t ws_size,
                              hipStream_t stream) {
    const float* x = (const float*)d_in[0];   // [256,1024]
    const float* T = (const float*)d_in[1];   // [1024,4096]
    float* out = (float*)d_out;               // [256,1152]

    const size_t NEED = 2 * MT_ELEMS * 4 + (size_t)CHUNKS * OUT_F * N_SAMP * 4; // 9 MiB

    if (ws_size >= NEED) {
        float* Mt   = (float*)d_ws;                       // 2 halves: 8 MiB
        float* part = Mt + 2 * MT_ELEMS;                  // 1 MiB

        gemm_fused<<<dim3(JTOT / 64, N_SAMP / 64, 2), 256, 0, stream>>>(x, T, out, Mt);
        dist_part<<<dim3(OUT_F, CHUNKS), 256, 0, stream>>>(Mt, part);
        dist_reduce<<<OUT_F, 256, 0, stream>>>(part, out);
    } else {
        float* M = (float*)d_ws;              // 4 MiB (proven available in r1)
        copy_init_kernel<<<N_SAMP, 256, 0, stream>>>(x, out);
        dim3 ggrid(JTOT / BN, N_SAMP / BM);
        gemm_kernel<<<ggrid, 256, 0, stream>>>(x, T, M);
        dist_kernel<<<OUT_F * 4, 256, 0, stream>>>(M, out);
    }
}

// Round 12
// 97.333 us; speedup vs baseline: 1.5806x; 1.0618x over previous
//
#include <hip/hip_runtime.h>

typedef unsigned short u16;
typedef __attribute__((ext_vector_type(8))) short short8_t;   // 8 bf16 = 4 VGPRs
typedef __attribute__((ext_vector_type(4))) float f32x4;      // MFMA accumulator

#define N_SAMP 256
#define IN_F   1024
#define OUT_F  128
#define KDIM   32
#define JTOT   (OUT_F * KDIM)   // 4096
#define OUT_ROW (IN_F + OUT_F)  // 1152
#define MT_ELEMS ((size_t)JTOT * N_SAMP)   // one Mt half: 1M floats = 4 MiB

#define NKZ    4                 // split-K factor
#define KPERKZ (IN_F / NKZ)      // 256
#define KSTEP  64
#define NSTEPS (KPERKZ / KSTEP)  // 4
#define LDB2   72                // u16: 64 k + 8 pad; row stride 144 B (16B-aligned)

#define CHUNKS 8                 // m-chunks for dist partials
#define MPC    32                // m per chunk (per block)
#define MPW    8                 // m per wave

__device__ __forceinline__ u16 f2bf(float f) {
    union { float f; unsigned u; } v; v.f = f;
    unsigned r = v.u + 0x7FFFu + ((v.u >> 16) & 1u);   // RNE
    return (u16)(r >> 16);
}
__device__ __forceinline__ unsigned pack2(float lo, float hi) {
    return (unsigned)f2bf(lo) | ((unsigned)f2bf(hi) << 16);
}

// ===========================================================================
// MAIN PATH: fused convert+transpose+GEMM with BN=256 (T read ONCE total),
// split-K x4 -> sum_halves -> dist (r4-proven single-source) -> reduce.
// ===========================================================================

// grid (64 j, 4 kz) = 256 blocks, 512 thr = 8 waves (wj = w>>2 in {0,1} j-half,
// wn = w&3 in {0..3} n-quarter). Block tile 64j x 256n x 256k. K-step 64, dbuf.
__global__ __launch_bounds__(512) void gemm_fused2(const float* __restrict__ x,
                                                   const float* __restrict__ T,
                                                   float* __restrict__ out,
                                                   float* __restrict__ Mt) {
    __shared__ u16 Bs[2][64 * LDB2];    // j rows (transposed from T), 2 x 9216 B
    __shared__ u16 As[2][256 * LDB2];   // n rows (from x),            2 x 36864 B
    const int t = threadIdx.x, w = t >> 6, l = t & 63;
    const int wj = w >> 2, wn = w & 3;
    const int jb = blockIdx.x * 64;
    const int kz = blockIdx.y, kbase = kz * KPERKZ;
    float* Mth = Mt + (size_t)kz * MT_ELEMS;

    // fused x -> out[:, :1024] copy (kz==0 plane: 64 blocks x 4 rows each)
    if (kz == 0) {
        const int row = blockIdx.x * 4 + (t >> 7);
        const int c  = t & 127;
        const float4* src = reinterpret_cast<const float4*>(x + (size_t)row * IN_F);
        float4* dst = reinterpret_cast<float4*>(out + (size_t)row * OUT_ROW);
        dst[c] = src[c];
        dst[c + 128] = src[c + 128];
    }

    // staging roles: t<256 also stages T (4 k-rows x 1 float4 of j each);
    // ALL threads stage x (1 n-row-half: 8 float4 of k).
    const int tj  = t & 15;          // j-quad (4 j)
    const int tk4 = (t >> 4) * 4;    // k-row base (t<256 -> 0..60)
    const int xn  = t >> 1;          // n row 0..255
    const int xh  = t & 1;           // k half (32 floats)

    f32x4 acc[2][4];
#pragma unroll
    for (int a = 0; a < 2; ++a)
#pragma unroll
        for (int b = 0; b < 4; ++b) acc[a][b] = (f32x4){0.f, 0.f, 0.f, 0.f};

    float4 ta[4], xv[8];
    auto LOADG = [&](int it) {
        const int k0 = kbase + it * KSTEP;
        if (t < 256) {
#pragma unroll
            for (int r = 0; r < 4; ++r)
                ta[r] = *reinterpret_cast<const float4*>(&T[(size_t)(k0 + tk4 + r) * JTOT + jb + tj * 4]);
        }
#pragma unroll
        for (int i = 0; i < 8; ++i)
            xv[i] = *reinterpret_cast<const float4*>(&x[(size_t)xn * IN_F + k0 + xh * 32 + i * 4]);
    };
    auto STOREB = [&](int b) {
        if (t < 256) {   // transpose-write T: Bs[j][k], k-pairs packed
            const float* f0 = reinterpret_cast<const float*>(&ta[0]);
            const float* f1 = reinterpret_cast<const float*>(&ta[1]);
            const float* f2 = reinterpret_cast<const float*>(&ta[2]);
            const float* f3 = reinterpret_cast<const float*>(&ta[3]);
#pragma unroll
            for (int c = 0; c < 4; ++c) {
                uint2 pv = make_uint2(pack2(f0[c], f1[c]), pack2(f2[c], f3[c]));
                *reinterpret_cast<uint2*>(&Bs[b][(tj * 4 + c) * LDB2 + tk4]) = pv;
            }
        }
        // x: k-linear vector writes As[n][k]
#pragma unroll
        for (int i = 0; i < 4; ++i) {
            const float* g0 = reinterpret_cast<const float*>(&xv[2 * i]);
            const float* g1 = reinterpret_cast<const float*>(&xv[2 * i + 1]);
            uint4 pv = make_uint4(pack2(g0[0], g0[1]), pack2(g0[2], g0[3]),
                                  pack2(g1[0], g1[1]), pack2(g1[2], g1[3]));
            *reinterpret_cast<uint4*>(&As[b][xn * LDB2 + xh * 32 + i * 8]) = pv;
        }
    };

    LOADG(0); STOREB(0); __syncthreads();

    for (int it = 0; it < NSTEPS; ++it) {
        const int cur = it & 1;
        if (it < NSTEPS - 1) LOADG(it + 1);     // next tile's global loads early
#pragma unroll
        for (int s = 0; s < 2; ++s) {
            const int co = s * 32 + 8 * (l >> 4);   // same assumed k-map A and B
            short8_t a0 = *reinterpret_cast<const short8_t*>(&Bs[cur][(wj * 32 +      (l & 15)) * LDB2 + co]);
            short8_t a1 = *reinterpret_cast<const short8_t*>(&Bs[cur][(wj * 32 + 16 + (l & 15)) * LDB2 + co]);
#pragma unroll
            for (int ni = 0; ni < 4; ++ni) {
                short8_t bn = *reinterpret_cast<const short8_t*>(&As[cur][(wn * 64 + ni * 16 + (l & 15)) * LDB2 + co]);
                acc[0][ni] = __builtin_amdgcn_mfma_f32_16x16x32_bf16(a0, bn, acc[0][ni], 0, 0, 0);
                acc[1][ni] = __builtin_amdgcn_mfma_f32_16x16x32_bf16(a1, bn, acc[1][ni], 0, 0, 0);
            }
        }
        if (it < NSTEPS - 1) STOREB(cur ^ 1);   // write OTHER buffer: no hazard
        __syncthreads();                        // single barrier per K-step
    }

    // C/D layout (m89-verified): col = lane&15 (n), row = 4*(lane>>4)+reg (j)
    const int jrow = jb + wj * 32 + (l >> 4) * 4;
#pragma unroll
    for (int ni = 0; ni < 4; ++ni) {
        const int ncol = wn * 64 + ni * 16 + (l & 15);
#pragma unroll
        for (int r = 0; r < 4; ++r) {
            Mth[(size_t)(jrow + r     ) * N_SAMP + ncol] = acc[0][ni][r];
            Mth[(size_t)(jrow + 16 + r) * N_SAMP + ncol] = acc[1][ni][r];
        }
    }
}

// --- collapse the 4 kz-halves: Mtsum = sum_h Mt[h] (1024 blocks, 1 f4/thr) ---
__global__ __launch_bounds__(256) void sum_halves(const float* __restrict__ Mt,
                                                  float* __restrict__ Mtsum) {
    const size_t i = (size_t)blockIdx.x * 256 + threadIdx.x;   // float4 index
    const float4* h0 = reinterpret_cast<const float4*>(Mt);
    const float4* h1 = h0 + MT_ELEMS / 4;
    const float4* h2 = h1 + MT_ELEMS / 4;
    const float4* h3 = h2 + MT_ELEMS / 4;
    float4 a = h0[i], b = h1[i], c = h2[i], d = h3[i];
    float4 s = make_float4(a.x + b.x + c.x + d.x, a.y + b.y + c.y + d.y,
                           a.z + b.z + c.z + d.z, a.w + b.w + c.w + d.w);
    reinterpret_cast<float4*>(Mtsum)[i] = s;
}

// --- dist stage 1: per-(o, m-chunk) partials (r4-proven single-source) ---
__global__ __launch_bounds__(256) void dist_part(const float* __restrict__ Mt,
                                                 float* __restrict__ part) {
    __shared__ float Mo[MPC][36];        // [m][k], row stride 144 B
    __shared__ float Pred[4][N_SAMP];    // per-wave partials
    const int t = threadIdx.x, w = t >> 6, l = t & 63;
    const int o  = blockIdx.x;           // 0..127
    const int mb = blockIdx.y * MPC;     // 0..224

    {   // stage Mo[32][32]: coalesced (lanes = consecutive m)
        const int m = t & 31, kb = (t >> 5) * 4;
#pragma unroll
        for (int kk = 0; kk < 4; ++kk)
            Mo[m][kb + kk] = Mt[(size_t)(o * KDIM + kb + kk) * N_SAMP + mb + m];
    }
    __syncthreads();

    float accd[4][MPW];                  // partial L1 distances [row][m]
#pragma unroll
    for (int r = 0; r < 4; ++r)
#pragma unroll
        for (int m = 0; m < MPW; ++m) accd[r][m] = 0.f;

#pragma unroll
    for (int kh = 0; kh < 4; ++kh) {     // k in 4 chunks of 8
        float r0[8], r1[8], r2[8], r3[8];
#pragma unroll
        for (int k = 0; k < 8; ++k) {    // lane-coalesced column loads
            const float* p = Mt + (size_t)(o * KDIM + kh * 8 + k) * N_SAMP + l;
            r0[k] = p[0]; r1[k] = p[64]; r2[k] = p[128]; r3[k] = p[192];
        }
#pragma unroll
        for (int m = 0; m < MPW; ++m) {
            float mo[8];
#pragma unroll
            for (int i = 0; i < 2; ++i)  // wave-uniform broadcast reads
                *reinterpret_cast<float4*>(&mo[i * 4]) =
                    *reinterpret_cast<const float4*>(&Mo[w * MPW + m][kh * 8 + i * 4]);
#pragma unroll
            for (int k = 0; k < 8; ++k) {
                accd[0][m] += fabsf(r0[k] - mo[k]);
                accd[1][m] += fabsf(r1[k] - mo[k]);
                accd[2][m] += fabsf(r2[k] - mo[k]);
                accd[3][m] += fabsf(r3[k] - mo[k]);
            }
        }
    }

    float a0 = 0.f, a1 = 0.f, a2 = 0.f, a3 = 0.f;
#pragma unroll
    for (int m = 0; m < MPW; ++m) {
        a0 += __expf(-accd[0][m]); a1 += __expf(-accd[1][m]);
        a2 += __expf(-accd[2][m]); a3 += __expf(-accd[3][m]);
    }
    Pred[w][l] = a0; Pred[w][l + 64] = a1; Pred[w][l + 128] = a2; Pred[w][l + 192] = a3;
    __syncthreads();

    {   // sum the 4 waves' m-subranges; coalesced write part[chunk][o][n]
        float s = Pred[0][t] + Pred[1][t] + Pred[2][t] + Pred[3][t];
        part[(size_t)blockIdx.y * (OUT_F * N_SAMP) + o * N_SAMP + t] = s;
    }
}

// --- dist stage 2: sum 8 chunks, subtract self-term ---
__global__ __launch_bounds__(256) void dist_reduce(const float* __restrict__ part,
                                                   float* __restrict__ out) {
    const int o = blockIdx.x, n = threadIdx.x;
    float s = -1.0f;
#pragma unroll
    for (int c = 0; c < CHUNKS; ++c)
        s += part[(size_t)c * (OUT_F * N_SAMP) + o * N_SAMP + n];
    out[(size_t)n * OUT_ROW + IN_F + o] = s;
}

// ===========================================================================
// FALLBACK PATH (round-1 proven kernels; used only if ws is too small)
// ===========================================================================
__global__ __launch_bounds__(256) void copy_init_kernel(const float* __restrict__ x,
                                                        float* __restrict__ out) {
    int n = blockIdx.x, t = threadIdx.x;
    reinterpret_cast<float4*>(out + (size_t)n * OUT_ROW)[t] =
        reinterpret_cast<const float4*>(x + (size_t)n * IN_F)[t];
    if (t < OUT_F) out[(size_t)n * OUT_ROW + IN_F + t] = -1.0f;
}

#define BM 64
#define BN 64
#define BK 16
#define AS_STRIDE 68
__global__ __launch_bounds__(256) void gemm_kernel(const float* __restrict__ x,
                                                   const float* __restrict__ T,
                                                   float* __restrict__ M) {
    __shared__ float As_[BK][AS_STRIDE];
    __shared__ float Bs_[BK][BN];
    const int jb = blockIdx.x * BN, nb = blockIdx.y * BM;
    const int t = threadIdx.x, tx = t & 15, ty = t >> 4;
    float acc[4][4] = {};
    for (int k0 = 0; k0 < IN_F; k0 += BK) {
        {
            int row = t >> 2, cg = (t & 3) * 4;
            float4 v = *reinterpret_cast<const float4*>(&x[(size_t)(nb + row) * IN_F + k0 + cg]);
            As_[cg + 0][row] = v.x; As_[cg + 1][row] = v.y;
            As_[cg + 2][row] = v.z; As_[cg + 3][row] = v.w;
        }
        {
            int r = t >> 4, cg = (t & 15) * 4;
            *reinterpret_cast<float4*>(&Bs_[r][cg]) =
                *reinterpret_cast<const float4*>(&T[(size_t)(k0 + r) * JTOT + jb + cg]);
        }
        __syncthreads();
#pragma unroll
        for (int kk = 0; kk < BK; ++kk) {
            float4 av = *reinterpret_cast<const float4*>(&As_[kk][ty * 4]);
            float4 bv = *reinterpret_cast<const float4*>(&Bs_[kk][tx * 4]);
            float a[4] = {av.x, av.y, av.z, av.w}, b[4] = {bv.x, bv.y, bv.z, bv.w};
#pragma unroll
            for (int i = 0; i < 4; ++i)
#pragma unroll
                for (int j = 0; j < 4; ++j) acc[i][j] += a[i] * b[j];
        }
        __syncthreads();
    }
#pragma unroll
    for (int i = 0; i < 4; ++i) {
        int n = nb + ty * 4 + i;
        float4 v = make_float4(acc[i][0], acc[i][1], acc[i][2], acc[i][3]);
        *reinterpret_cast<float4*>(&M[(size_t)n * JTOT + jb + tx * 4]) = v;
    }
}

__global__ __launch_bounds__(256) void dist_kernel(const float* __restrict__ M,
                                                   float* __restrict__ out) {
    __shared__ float Mo_[64][KDIM];
    const int o = blockIdx.x >> 2, chunk = blockIdx.x & 3, t = threadIdx.x;
    float r[KDIM];
    const float4* mrow = reinterpret_cast<const float4*>(&M[(size_t)t * JTOT + o * KDIM]);
#pragma unroll
    for (int f = 0; f < 8; ++f) {
        float4 v = mrow[f];
        r[f*4+0]=v.x; r[f*4+1]=v.y; r[f*4+2]=v.z; r[f*4+3]=v.w;
    }
    const int mbase = chunk * 64;
    {
        int row = t >> 3, f4 = t & 7;
        *reinterpret_cast<float4*>(&Mo_[row][f4*4]) =
            *reinterpret_cast<const float4*>(&M[(size_t)(mbase+row)*JTOT + o*KDIM + f4*4]);
        *reinterpret_cast<float4*>(&Mo_[row+32][f4*4]) =
            *reinterpret_cast<const float4*>(&M[(size_t)(mbase+row+32)*JTOT + o*KDIM + f4*4]);
    }
    __syncthreads();
    float acc = 0.f;
    for (int m = 0; m < 64; ++m) {
        float d = 0.f;
#pragma unroll
        for (int k = 0; k < KDIM; ++k) d += fabsf(r[k] - Mo_[m][k]);
        acc += __expf(-d);
    }
    atomicAdd(&out[(size_t)t * OUT_ROW + IN_F + o], acc);
}

// ===========================================================================
extern "C" void kernel_launch(void* const* d_in, const int* in_sizes, int n_in,
                              void* d_out, int out_size, void* d_ws, size_t ws_size,
                              hipStream_t stream) {
    const float* x = (const float*)d_in[0];   // [256,1024]
    const float* T = (const float*)d_in[1];   // [1024,4096]
    float* out = (float*)d_out;               // [256,1152]

    // ws layout: Mt[4 halves] 16 MiB | Mtsum 4 MiB | part 1 MiB
    const size_t NEED = (NKZ + 1) * MT_ELEMS * 4 + (size_t)CHUNKS * OUT_F * N_SAMP * 4;

    if (ws_size >= NEED) {
        float* Mt    = (float*)d_ws;
        float* Mtsum = Mt + (size_t)NKZ * MT_ELEMS;
        float* part  = Mtsum + MT_ELEMS;

        gemm_fused2<<<dim3(JTOT / 64, NKZ), 512, 0, stream>>>(x, T, out, Mt);
        sum_halves<<<MT_ELEMS / 4 / 256, 256, 0, stream>>>(Mt, Mtsum);
        dist_part<<<dim3(OUT_F, CHUNKS), 256, 0, stream>>>(Mtsum, part);
        dist_reduce<<<OUT_F, 256, 0, stream>>>(part, out);
    } else {
        float* M = (float*)d_ws;              // 4 MiB (proven available in r1)
        copy_init_kernel<<<N_SAMP, 256, 0, stream>>>(x, out);
        dim3 ggrid(JTOT / BN, N_SAMP / BM);
        gemm_kernel<<<ggrid, 256, 0, stream>>>(x, T, M);
        dist_kernel<<<OUT_F * 4, 256, 0, stream>>>(M, out);
    }
}